// Round 6
// baseline (210.241 us; speedup 1.0000x reference)
//
#include <hip/hip_runtime.h>
#include <hip/hip_cooperative_groups.h>
#include <stdint.h>

namespace cg = cooperative_groups;

typedef unsigned long long u64;
typedef unsigned int u32;

#define N_ANCH 36864
#define NBLK 36         // 36 x 1024 = 36864
#define WGRID 64
#define A_PER 9
#define KTOP 6000
#define NOUT 300
#define NBIN 8192       // monotone distribution-aware bins (max used = 1279)
#define NCHK 94         // ceil(6000/64)
#define INF_BIN 0

// Base anchors from py-faster-rcnn generate_anchors (scales 8,16,32; ratios .5,1,2), exact integers.
__constant__ float c_ax1[9] = {-84.f,-176.f,-360.f,-56.f,-120.f,-248.f,-36.f,-80.f,-168.f};
__constant__ float c_ay1[9] = {-40.f,-88.f,-184.f,-56.f,-120.f,-248.f,-80.f,-168.f,-344.f};
__constant__ float c_aw[9]  = {184.f,368.f,736.f,128.f,256.f,512.f,88.f,176.f,352.f};
__constant__ float c_ah[9]  = {96.f,192.f,384.f,128.f,256.f,512.f,176.f,352.f,704.f};

// Monotone bin of ordered-float score word u. Scores sigmoid(l1-l0) concentrate in
// [0.5,1) = one float octave -> 1024 fine bins there (11 mantissa bits dropped).
__device__ __forceinline__ u32 binof(u32 u) {
    if (u < 0x80000000u) return 0u;                               // -inf (invalid)
    if (u < 0xBF000000u) return 1u + ((u - 0x80000000u) >> 22);   // s<0.5 : 1..252
    return 256u + ((u - 0xBF000000u) >> 11);                      // s>=0.5: 256..1279
}

// 8x8 grid of 128-px cells occupancy signature. Exact-safe NMS prefilter:
// sig-disjoint => x- or y-ranges disjoint => iw<1 or ih<1 => IoU < 1/31 < 0.7
// (areas >= 16x16 via MIN_SIZE). No false negatives.
__device__ __forceinline__ u64 sigof(float4 b) {
    int cx0 = (int)b.x >> 7, cx1 = (int)b.z >> 7;
    int cy0 = (int)b.y >> 7, cy1 = (int)b.w >> 7;
    u32 colm = (2u << cx1) - (1u << cx0);                         // bits cx0..cx1
    u64 rowsel = ((~0ULL) >> (8 * (7 - cy1))) & ((~0ULL) << (8 * cy0));
    return rowsel & (0x0101010101010101ULL * (u64)colm);
}

__device__ __forceinline__ bool iou_gt(float4 a, float areaA, float4 b, float areaB) {
    float ix1 = fmaxf(a.x, b.x), iy1 = fmaxf(a.y, b.y);
    float ix2 = fminf(a.z, b.z), iy2 = fminf(a.w, b.w);
    float iw = fmaxf(ix2 - ix1 + 1.0f, 0.0f);
    float ih = fmaxf(iy2 - iy1 + 1.0f, 0.0f);
    float inter = iw * ih;
    float iou = inter / (areaA + areaB - inter);
    return iou > 0.7f;
}

// One cooperative kernel: proposal -> hist -> scan -> scatter -> rank -> NMS -> out.
__global__ __launch_bounds__(1024) void fused_kernel(
    const float* __restrict__ cls, const float* __restrict__ dlt,
    u64* __restrict__ scat, float4* __restrict__ boxes,
    float4* __restrict__ topBoxes, u32* __restrict__ hist,
    u32* __restrict__ cursor, u32* __restrict__ binStart,
    u32* __restrict__ gEV, float* __restrict__ out)
{
    cg::grid_group grid = cg::this_grid();
    const int t = threadIdx.x;
    const int gid = (int)blockIdx.x * 1024 + t;

    __shared__ u32 lh[NBIN];          // 32 KB: P1 LDS histogram
    __shared__ u32 sh[1024];          // scan / fallback prefix buffer

    // ---- P0 (overlapped with P1 compute): zero global hist+cursor (adjacent) ----
    if (gid < 2 * NBIN) hist[gid] = 0;
    if (gid == 0) gEV[1] = KTOP;      // V init (lowered by rank via atomicMin)
    for (int b = t; b < NBIN; b += 1024) lh[b] = 0;
    __syncthreads();

    // ---- P1: proposal (one thread per anchor), LDS histogram ----
    const int i = gid;
    {
        int a  = i % A_PER;
        int hw = i / A_PER;
        int wx = hw % WGRID;
        int hy = hw / WGRID;
        float l0 = cls[hw * 18 + 2 * a];
        float l1 = cls[hw * 18 + 2 * a + 1];
        float m  = fmaxf(l0, l1);
        float e0 = expf(l0 - m), e1 = expf(l1 - m);
        float s  = e1 / (e0 + e1);

        const float* d = dlt + hw * 36 + 4 * a;
        float dx = d[0], dy = d[1], dw = d[2], dh = d[3];
        float aw = c_aw[a], ah = c_ah[a];
        float axc = (c_ax1[a] + 16.f * (float)wx) + 0.5f * aw;
        float ayc = (c_ay1[a] + 16.f * (float)hy) + 0.5f * ah;
        float pxc = dx * aw + axc;
        float pyc = dy * ah + ayc;
        float pw  = expf(dw) * aw;
        float ph  = expf(dh) * ah;
        float x1 = pxc - 0.5f * pw, y1 = pyc - 0.5f * ph;
        float x2 = pxc + 0.5f * pw, y2 = pyc + 0.5f * ph;
        x1 = fminf(fmaxf(x1, 0.f), 1023.f);
        x2 = fminf(fmaxf(x2, 0.f), 1023.f);
        y1 = fminf(fmaxf(y1, 0.f), 1023.f);
        y2 = fminf(fmaxf(y2, 0.f), 1023.f);
        bool valid = ((x2 - x1 + 1.f) >= 16.f) && ((y2 - y1 + 1.f) >= 16.f);
        float sc = valid ? s : -__builtin_huge_valf();

        u32 sb  = __float_as_uint(sc);
        u32 ord = (sb & 0x80000000u) ? ~sb : (sb | 0x80000000u);
        u64 key = ((u64)ord << 32) | (u32)(~(u32)i);     // key stays in registers
        boxes[i] = make_float4(x1, y1, x2, y2);

        u64 infb = __ballot(!valid);
        if (valid) {
            atomicAdd(&lh[binof(ord)], 1u);
        } else if ((t & 63) == __builtin_ctzll(infb)) {
            atomicAdd(&lh[INF_BIN], (u32)__popcll(infb));
        }
        __syncthreads();
        __threadfence();
        grid.sync();                                 // S1: global hist zeroed everywhere

        // merge LDS hist -> global
        for (int b = t; b < NBIN; b += 1024) {
            u32 v = lh[b];
            if (v) atomicAdd(&hist[b], v);
        }
        __threadfence();
        grid.sync();                                 // S2: hist complete

        // ---- P2: scan (block 0) ----
        if (blockIdx.x == 0) {
            int hi = NBIN - 1 - 8 * t;               // thread t owns bins [hi-7..hi], desc
            u32 cnt[8];
            u32 sum = 0;
#pragma unroll
            for (int k = 0; k < 8; ++k) { cnt[k] = hist[hi - k]; sum += cnt[k]; }
            sh[t] = sum;
            __syncthreads();
            for (int dd = 1; dd < 1024; dd <<= 1) {
                u32 v = (t >= dd) ? sh[t - dd] : 0;
                __syncthreads();
                sh[t] += v;
                __syncthreads();
            }
            u32 run = sh[t] - sum;                   // exclusive prefix (higher bins)
#pragma unroll
            for (int k = 0; k < 8; ++k) {
                int b = hi - k;
                binStart[b] = run;
                u32 end = run + cnt[k];
                if (run < KTOP && end >= KTOP) gEV[0] = end;
                run = end;
            }
        }
        __threadfence();
        grid.sync();                                 // S3: binStart/E ready

        // ---- P3: scatter (key from registers) ----
        {
            u32 b = binof(ord);
            u32 s0 = binStart[b];
            if (s0 < KTOP) {
                u32 p = s0 + atomicAdd(&cursor[b], 1u);
                scat[p] = key;
            }
        }
        __threadfence();
        grid.sync();                                 // S4: scat complete
    }

    // ---- P4: exact rank within bucket, gather topBoxes ----
    {
        u32 E = gEV[0];
        if (gid < (int)E) {
            u64 k = scat[gid];
            u32 b = binof((u32)(k >> 32));
            u32 s0 = binStart[b], c = hist[b];
            u32 r = s0;
            for (u32 j = s0; j < s0 + c; ++j) r += (scat[j] > k) ? 1u : 0u;
            if (r < KTOP) {
                int idx = (int)(~(u32)k);
                topBoxes[r] = boxes[idx];
                if (!(k >> 63)) atomicMin((int*)&gEV[1], (int)r);
            }
        }
    }
    __threadfence();
    grid.sync();                                     // S5: topBoxes + V ready

    // ---- P5: NMS + output (block 0 only) ----
    if (blockIdx.x != 0) return;

    __shared__ float4 cbox[2][64];
    __shared__ float  ca[2][64];
    __shared__ u64    csig[2][64];
    __shared__ u64    intra[2][64];
    __shared__ u64    supw[16];
    __shared__ u64    keepw[NCHK];
    __shared__ float4 kbox[NOUT];
    __shared__ float  karea[NOUT];
    __shared__ u64    ksig[NOUT];
    __shared__ int    s_nkept;

    const int lane = t & 63;
    const int w = t >> 6;              // 16 waves
    if (t < NCHK) keepw[t] = 0;
    if (t == 0) s_nkept = 0;
    const int V = (int)gEV[1];
    const int nchunks = (V + 63) >> 6;

    if (t < 64) {                      // stage chunk 0
        float4 b = make_float4(0.f, 0.f, 0.f, 0.f);
        if (t < V) b = topBoxes[t];
        cbox[0][t] = b;
        ca[0][t]   = (b.z - b.x + 1.f) * (b.w - b.y + 1.f);
        csig[0][t] = sigof(b);
        intra[0][t] = 0;
    }
    __syncthreads();

    for (int c = 0; c < nchunks; ++c) {
        const int p = c & 1;
        const int base = c * 64;
        const int csz = min(64, V - base);
        const int nk = s_nkept;
        // sup-by-kept: wave w tests kept k ≡ w (mod 16); sig prefilter first
        bool sup = false;
        if (lane < csz) {
            float4 bb = cbox[p][lane]; float ab = ca[p][lane]; u64 sg = csig[p][lane];
            for (int k = w; k < nk; k += 16) {
                if (sg & ksig[k]) {
                    if (iou_gt(bb, ab, kbox[k], karea[k])) { sup = true; break; }
                }
            }
        }
        u64 bal = __ballot(sup);
        if (lane == 0) supw[w] = bal;
        // intra-chunk mask: thread (i=lane, slice w) covers j>i with j%16==w
        if (lane < csz) {
            float4 bb = cbox[p][lane]; float ab = ca[p][lane]; u64 sg = csig[p][lane];
            u64 m = 0;
            int j0 = lane + 1;
            j0 += ((w - j0) % 16 + 16) % 16;
            for (int j = j0; j < csz; j += 16)
                if ((sg & csig[p][j]) && iou_gt(bb, ab, cbox[p][j], ca[p][j]))
                    m |= (1ULL << j);
            if (m) atomicOr(&intra[p][lane], m);
        }
        __syncthreads();                               // supw + intra ready
        if (w == 0) {
            // greedy resolve: rows in registers, broadcast via shfl; kb wave-uniform
            u64 row = intra[p][lane];
            u64 sup64 = 0;
#pragma unroll
            for (int q = 0; q < 16; ++q) sup64 |= supw[q];
            u64 alive = ~sup64;
            if (csz < 64) alive &= ((1ULL << csz) - 1ULL);
            u64 cand = alive, kb = 0;
            const int nk_base = s_nkept;
            int nk2 = nk_base;
            while (cand && nk2 < NOUT) {
                int b = __builtin_ctzll(cand);
                cand &= cand - 1;
                kb |= (1ULL << b);
                ++nk2;
                cand &= ~__shfl(row, b, 64);
            }
            if ((kb >> lane) & 1ULL) {                 // append kept in rank order
                int pos = nk_base + __popcll(kb & ((1ULL << lane) - 1ULL));
                kbox[pos]  = cbox[p][lane];
                karea[pos] = ca[p][lane];
                ksig[pos]  = csig[p][lane];
            }
            if (lane == 0) { keepw[c] = kb; s_nkept = nk2; }
        } else if (w == 1) {
            // stage next chunk concurrently with resolve
            int nb = base + 64 + lane;
            float4 b = make_float4(0.f, 0.f, 0.f, 0.f);
            if (nb < V) b = topBoxes[nb];
            cbox[p ^ 1][lane] = b;
            ca[p ^ 1][lane]   = (b.z - b.x + 1.f) * (b.w - b.y + 1.f);
            csig[p ^ 1][lane] = sigof(b);
            intra[p ^ 1][lane] = 0;
        }
        __syncthreads();                               // resolve+append+stage done
        if (s_nkept >= NOUT) break;
    }

    const int n1 = s_nkept;
    for (int r = t; r < n1; r += 1024) {
        float4 b = kbox[r];
        out[r * 5 + 0] = 0.f;
        out[r * 5 + 1] = b.x; out[r * 5 + 2] = b.y;
        out[r * 5 + 3] = b.z; out[r * 5 + 4] = b.w;
    }
    // fallback: <300 kept -> fill with -inf ties (suppressed OR rank>=V), ascending rank
    if (n1 < NOUT) {
        __syncthreads();
        const int per = 6;                             // 1024*6 >= 6000
        int r0 = t * per, r1 = min(r0 + per, KTOP);
        u32 cnt = 0;
        for (int r = r0; r < r1; ++r)
            cnt += ((keepw[r >> 6] >> (r & 63)) & 1ULL) ? 0u : 1u;
        sh[t] = cnt;
        __syncthreads();
        for (int dd = 1; dd < 1024; dd <<= 1) {
            u32 v = (t >= dd) ? sh[t - dd] : 0;
            __syncthreads();
            sh[t] += v;
            __syncthreads();
        }
        int ord2 = n1 + (int)(sh[t] - cnt);            // exclusive prefix of not-kept
        for (int r = r0; r < r1 && ord2 < NOUT; ++r) {
            if (!((keepw[r >> 6] >> (r & 63)) & 1ULL)) {
                float4 b = topBoxes[r];
                out[ord2 * 5 + 0] = 0.f;
                out[ord2 * 5 + 1] = b.x; out[ord2 * 5 + 2] = b.y;
                out[ord2 * 5 + 3] = b.z; out[ord2 * 5 + 4] = b.w;
                ++ord2;
            }
        }
    }
}

extern "C" void kernel_launch(void* const* d_in, const int* in_sizes, int n_in,
                              void* d_out, int out_size, void* d_ws, size_t ws_size,
                              hipStream_t stream) {
    const float* cls = (const float*)d_in[0];   // (1,64,64,18) f32
    const float* dlt = (const float*)d_in[1];   // (1,64,64,36) f32
    float* out = (float*)d_out;                 // 300x5 f32
    char* ws = (char*)d_ws;
    // layout (16B-aligned); hist and cursor adjacent -> single in-kernel zero phase
    u64*    scat     = (u64*)   (ws);                    // 294912
    float4* boxes    = (float4*)(ws + 294912);           // 589824
    float4* topBoxes = (float4*)(ws + 884736);           // 96000
    u32*    hist     = (u32*)   (ws + 980736);           // 32768
    u32*    cursor   = (u32*)   (ws + 1013504);          // 32768
    u32*    binStart = (u32*)   (ws + 1046272);          // 32768
    u32*    gEV      = (u32*)   (ws + 1079040);          // [0]=E, [1]=V

    void* args[] = { (void*)&cls, (void*)&dlt, (void*)&scat, (void*)&boxes,
                     (void*)&topBoxes, (void*)&hist, (void*)&cursor,
                     (void*)&binStart, (void*)&gEV, (void*)&out };
    hipLaunchCooperativeKernel((const void*)fused_kernel, dim3(NBLK), dim3(1024),
                               args, 0, stream);
}

// Round 7
// 178.084 us; speedup vs baseline: 1.1806x; 1.1806x over previous
//
#include <hip/hip_runtime.h>
#include <stdint.h>

typedef unsigned long long u64;
typedef unsigned int u32;

#define N_ANCH 36864
#define WGRID 64
#define A_PER 9
#define KTOP 6000
#define NOUT 300
#define NBIN 3072       // monotone distribution-aware bins (max used = 2304)
#define NSLICE 36
#define NCHK 94         // ceil(6000/64)
#define INF_BIN 0

// Base anchors from py-faster-rcnn generate_anchors (scales 8,16,32; ratios .5,1,2), exact integers.
__constant__ float c_ax1[9] = {-84.f,-176.f,-360.f,-56.f,-120.f,-248.f,-36.f,-80.f,-168.f};
__constant__ float c_ay1[9] = {-40.f,-88.f,-184.f,-56.f,-120.f,-248.f,-80.f,-168.f,-344.f};
__constant__ float c_aw[9]  = {184.f,368.f,736.f,128.f,256.f,512.f,88.f,176.f,352.f};
__constant__ float c_ah[9]  = {96.f,192.f,384.f,128.f,256.f,512.f,176.f,352.f,704.f};

// Monotone (order-preserving) bin of ordered-float score word u. Scores
// sigmoid(l1-l0) concentrate in [0.5,1] = one float octave -> 2049 fine bins.
__device__ __forceinline__ u32 binof(u32 u) {
    if (u < 0x80000000u) return 0u;                               // -inf (invalid)
    if (u < 0xBF000000u) return 1u + ((u - 0x80000000u) >> 22);   // s<0.5 : 1..252
    return 256u + ((u - 0xBF000000u) >> 12);                      // s>=0.5: 256..2304
}

// 8x8 grid of 128-px cells occupancy signature. Exact-safe NMS prefilter:
// sig-disjoint => x- or y-ranges disjoint => iw<1 or ih<1 => IoU < 1/31 < 0.7.
__device__ __forceinline__ u64 sigof(float4 b) {
    int cx0 = (int)b.x >> 7, cx1 = (int)b.z >> 7;
    int cy0 = (int)b.y >> 7, cy1 = (int)b.w >> 7;
    u32 colm = (2u << cx1) - (1u << cx0);
    u64 rowsel = ((~0ULL) >> (8 * (7 - cy1))) & ((~0ULL) << (8 * cy0));
    return rowsel & (0x0101010101010101ULL * (u64)colm);
}

__device__ __forceinline__ u64 shfl64(u64 v, int src) {
    u32 lo = (u32)__shfl((int)(v & 0xFFFFFFFFu), src, 64);
    u32 hi = (u32)__shfl((int)(v >> 32), src, 64);
    return ((u64)hi << 32) | lo;
}

__device__ __forceinline__ bool iou_gt(float4 a, float areaA, float4 b, float areaB) {
    float ix1 = fmaxf(a.x, b.x), iy1 = fmaxf(a.y, b.y);
    float ix2 = fminf(a.z, b.z), iy2 = fminf(a.w, b.w);
    float iw = fmaxf(ix2 - ix1 + 1.0f, 0.0f);
    float ih = fmaxf(iy2 - iy1 + 1.0f, 0.0f);
    float inter = iw * ih;
    float iou = inter / (areaA + areaB - inter);
    return iou > 0.7f;
}

// K1: 36 blocks x 1024 = one thread per anchor. Per-block PRIVATE hist slice
// (plain stores, no global atomics, no pre-zeroing needed).
__global__ __launch_bounds__(1024) void proposal_kernel(const float* __restrict__ cls,
                                                        const float* __restrict__ dlt,
                                                        u32* __restrict__ ords,
                                                        float4* __restrict__ boxes,
                                                        u32* __restrict__ slices) {
    __shared__ u32 lh[NBIN];
    const int t = threadIdx.x;
    for (int b = t; b < NBIN; b += 1024) lh[b] = 0;
    __syncthreads();

    const int i = (int)blockIdx.x * 1024 + t;
    int a  = i % A_PER;
    int hw = i / A_PER;
    int wx = hw % WGRID;
    int hy = hw / WGRID;

    float l0 = cls[hw * 18 + 2 * a];
    float l1 = cls[hw * 18 + 2 * a + 1];
    float m  = fmaxf(l0, l1);
    float e0 = expf(l0 - m), e1 = expf(l1 - m);
    float s  = e1 / (e0 + e1);

    const float* d = dlt + hw * 36 + 4 * a;
    float dx = d[0], dy = d[1], dw = d[2], dh = d[3];
    float aw = c_aw[a], ah = c_ah[a];
    float axc = (c_ax1[a] + 16.f * (float)wx) + 0.5f * aw;
    float ayc = (c_ay1[a] + 16.f * (float)hy) + 0.5f * ah;
    float pxc = dx * aw + axc;
    float pyc = dy * ah + ayc;
    float pw  = expf(dw) * aw;
    float ph  = expf(dh) * ah;
    float x1 = pxc - 0.5f * pw, y1 = pyc - 0.5f * ph;
    float x2 = pxc + 0.5f * pw, y2 = pyc + 0.5f * ph;
    x1 = fminf(fmaxf(x1, 0.f), 1023.f);
    x2 = fminf(fmaxf(x2, 0.f), 1023.f);
    y1 = fminf(fmaxf(y1, 0.f), 1023.f);
    y2 = fminf(fmaxf(y2, 0.f), 1023.f);
    bool valid = ((x2 - x1 + 1.f) >= 16.f) && ((y2 - y1 + 1.f) >= 16.f);
    float sc = valid ? s : -__builtin_huge_valf();

    u32 sb  = __float_as_uint(sc);
    u32 ord = (sb & 0x80000000u) ? ~sb : (sb | 0x80000000u);
    ords[i]  = ord;
    boxes[i] = make_float4(x1, y1, x2, y2);

    u64 infb = __ballot(!valid);
    if (valid) {
        atomicAdd(&lh[binof(ord)], 1u);
    } else if ((t & 63) == __builtin_ctzll(infb)) {
        atomicAdd(&lh[INF_BIN], (u32)__popcll(infb));
    }
    __syncthreads();
    u32* my = slices + (int)blockIdx.x * NBIN;
    for (int b = t; b < NBIN; b += 1024) my[b] = lh[b];
}

// K2: single block, 1024 threads. merge-hist -> scan -> scatter -> rank -> NMS -> out.
__global__ __launch_bounds__(1024) void select_nms_kernel(const u32* __restrict__ ords,
                                                          const float4* __restrict__ boxes,
                                                          const u32* __restrict__ slices,
                                                          u64* __restrict__ scat,
                                                          float4* __restrict__ topBoxes,
                                                          float* __restrict__ out) {
    __shared__ u32 sBinStart[NBIN];
    __shared__ u32 sHist[NBIN];
    __shared__ u32 sCursor[NBIN];     // also fallback-scan scratch
    __shared__ u32 swsum[16];
    __shared__ u64 intra[2][64];
    __shared__ u64 supw[16];
    __shared__ u64 keepw[NCHK];
    __shared__ float4 kbox[NOUT];
    __shared__ float  karea[NOUT];
    __shared__ u64    ksig[NOUT];
    __shared__ int sE, sV, s_nkept, s_oldn;

    const int t = threadIdx.x;
    const int lane = t & 63;
    const int w = t >> 6;             // 16 waves

    // ---- A: merge 36 slices, descending exclusive scan over 3072 bins ----
    if (t == 0) { sV = KTOP; sE = KTOP; s_nkept = 0; s_oldn = 0; }
    if (t < NCHK) keepw[t] = 0;
    if (t < 64) { intra[0][t] = 0; intra[1][t] = 0; }
    const int hi = NBIN - 1 - 3 * t;  // thread t owns bins hi, hi-1, hi-2 (descending)
    u32 cnt0 = 0, cnt1 = 0, cnt2 = 0;
    for (int s = 0; s < NSLICE; ++s) {
        const u32* sl = slices + s * NBIN;
        cnt0 += sl[hi]; cnt1 += sl[hi - 1]; cnt2 += sl[hi - 2];
    }
    sHist[hi] = cnt0; sHist[hi - 1] = cnt1; sHist[hi - 2] = cnt2;
    u32 sum3 = cnt0 + cnt1 + cnt2;
    u32 x = sum3;                     // wave-inclusive scan (shfl, no barriers)
    for (int d = 1; d < 64; d <<= 1) {
        u32 y = __shfl_up(x, d, 64);
        if (lane >= d) x += y;
    }
    if (lane == 63) swsum[w] = x;
    for (int b = t; b < NBIN; b += 1024) sCursor[b] = 0;
    __syncthreads();
    if (t == 0) {
        u32 run0 = 0;
        for (int q = 0; q < 16; ++q) { u32 v = swsum[q]; swsum[q] = run0; run0 += v; }
    }
    __syncthreads();
    u32 run = swsum[w] + x - sum3;    // sum of all higher bins (exclusive)
    u32 e0 = run + cnt0;
    sBinStart[hi] = run;
    if (run < KTOP && e0 >= KTOP) sE = (int)e0;     // unique boundary bucket
    u32 e1 = e0 + cnt1;
    sBinStart[hi - 1] = e0;
    if (e0 < KTOP && e1 >= KTOP) sE = (int)e1;
    u32 e2 = e1 + cnt2;
    sBinStart[hi - 2] = e1;
    if (e1 < KTOP && e2 >= KTOP) sE = (int)e2;
    __syncthreads();

    // ---- B: scatter keys of buckets starting before rank KTOP ----
    for (int i2 = t; i2 < N_ANCH; i2 += 1024) {
        u32 ov = ords[i2];
        u32 b = binof(ov);
        u32 s0 = sBinStart[b];
        if (s0 < KTOP) {
            u32 pos = s0 + atomicAdd(&sCursor[b], 1u);
            scat[pos] = ((u64)ov << 32) | (u32)(~(u32)i2);
        }
    }
    __syncthreads();

    // ---- C: exact rank within bucket (keys unique), gather topBoxes[rank], find V ----
    const int E = sE;
    for (int i2 = t; i2 < E; i2 += 1024) {
        u64 k = scat[i2];
        u32 b = binof((u32)(k >> 32));
        u32 s0 = sBinStart[b], c = sHist[b];
        u32 r = s0;
        for (u32 j = s0; j < s0 + c; ++j) r += (scat[j] > k) ? 1u : 0u;
        if (r < (u32)KTOP) {
            int idx = (int)(~(u32)k);
            topBoxes[r] = boxes[idx];
            if (!(k >> 63)) atomicMin(&sV, (int)r);   // first -inf rank => V
        }
    }
    __syncthreads();

    // ---- D: greedy NMS. Kept sigs in registers (lane s of wave w = kept w+16s);
    //      shfl broadcasts replace the per-kept LDS reads; IoU only on sig-hit. ----
    const int V = sV;
    const int nchunks = (V + 63) >> 6;
    u64 myksig = 0;

    for (int c = 0; c < nchunks; ++c) {
        const int p = c & 1;
        const int base = c * 64;
        const int csz = min(64, V - base);
        float4 bb = make_float4(0.f, 0.f, 0.f, 0.f);
        if (lane < csz) bb = topBoxes[base + lane];       // L1-hot, all 16 waves
        float ab = (bb.z - bb.x + 1.f) * (bb.w - bb.y + 1.f);
        u64 sg = sigof(bb);
        const int nk = s_nkept;
        // sup-by-kept: wave w covers kept k ≡ w (mod 16); sig from regs via shfl
        bool sup = false;
        int s = 0;
        for (int k = w; k < nk; k += 16, ++s) {
            u64 sigk = shfl64(myksig, s);
            if (sg & sigk) {
                float4 kb4 = kbox[k];
                float ka = karea[k];
                if (iou_gt(bb, ab, kb4, ka)) sup = true;
            }
        }
        if (lane >= csz) sup = false;
        u64 bal = __ballot(sup);
        if (lane == 0) supw[w] = bal;
        if (w == 14 && c + 1 < nchunks) intra[p ^ 1][lane] = 0;  // zero next buffer
        // intra-chunk pairs: wave w covers jj ∈ {w, w+16, w+32, w+48}, data via shfl
        u64 m = 0;
#pragma unroll
        for (int q = 0; q < 4; ++q) {
            int jj = w + 16 * q;
            u64 sgj = shfl64(sg, jj);
            float jx1 = __shfl(bb.x, jj, 64);
            float jy1 = __shfl(bb.y, jj, 64);
            float jx2 = __shfl(bb.z, jj, 64);
            float jy2 = __shfl(bb.w, jj, 64);
            float ja  = __shfl(ab,   jj, 64);
            if (lane < jj && jj < csz && (sg & sgj)) {
                float4 bj = make_float4(jx1, jy1, jx2, jy2);
                if (iou_gt(bb, ab, bj, ja)) m |= (1ULL << jj);
            }
        }
        if (m) atomicOr(&intra[p][lane], m);
        __syncthreads();                                  // B1: supw + intra ready
        if (w == 0) {
            u64 row = intra[p][lane];
            u64 sup64 = supw[0];
#pragma unroll
            for (int q = 1; q < 16; ++q) sup64 |= supw[q];
            u64 alive = ~sup64;
            if (csz < 64) alive &= ((1ULL << csz) - 1ULL);
            u64 cand = alive, kb = 0;
            const int nk0 = s_nkept;
            int nk2 = nk0;
            while (cand && nk2 < NOUT) {
                int b = __builtin_ctzll(cand);
                cand &= cand - 1;
                kb |= (1ULL << b);
                ++nk2;
                cand &= ~shfl64(row, b);
            }
            if ((kb >> lane) & 1ULL) {                    // append kept in rank order
                int pos = nk0 + __popcll(kb & ((1ULL << lane) - 1ULL));
                kbox[pos]  = bb;
                karea[pos] = ab;
                ksig[pos]  = sg;
            }
            if (lane == 0) { keepw[c] = kb; s_oldn = nk0; s_nkept = nk2; }
        }
        __syncthreads();                                  // B2: kept state visible
        const int newn = s_nkept, oldn = s_oldn;
        for (int pos = oldn; pos < newn; ++pos) {         // pull new sigs into regs
            if ((pos & 15) == w) {
                u64 v = ksig[pos];
                if (lane == (pos >> 4)) myksig = v;
            }
        }
        if (newn >= NOUT) break;
    }

    // ---- E: output blob (+ -inf tie fallback, ascending rank) ----
    const int n1 = s_nkept;
    for (int r = t; r < n1; r += 1024) {
        float4 b = kbox[r];
        out[r * 5 + 0] = 0.f;
        out[r * 5 + 1] = b.x; out[r * 5 + 2] = b.y;
        out[r * 5 + 3] = b.z; out[r * 5 + 4] = b.w;
    }
    if (n1 < NOUT) {
        __syncthreads();
        const int per = 6;                                // 1024*6 >= 6000
        int r0 = t * per, r1 = min(r0 + per, KTOP);
        u32 cntk = 0;
        for (int r = r0; r < r1; ++r)
            cntk += ((keepw[r >> 6] >> (r & 63)) & 1ULL) ? 0u : 1u;
        sCursor[t] = cntk;
        __syncthreads();
        for (int dd = 1; dd < 1024; dd <<= 1) {
            u32 v = (t >= dd) ? sCursor[t - dd] : 0;
            __syncthreads();
            sCursor[t] += v;
            __syncthreads();
        }
        int ord2 = n1 + (int)(sCursor[t] - cntk);         // exclusive prefix of not-kept
        for (int r = r0; r < r1 && ord2 < NOUT; ++r) {
            if (!((keepw[r >> 6] >> (r & 63)) & 1ULL)) {
                float4 b = topBoxes[r];
                out[ord2 * 5 + 0] = 0.f;
                out[ord2 * 5 + 1] = b.x; out[ord2 * 5 + 2] = b.y;
                out[ord2 * 5 + 3] = b.z; out[ord2 * 5 + 4] = b.w;
                ++ord2;
            }
        }
    }
}

extern "C" void kernel_launch(void* const* d_in, const int* in_sizes, int n_in,
                              void* d_out, int out_size, void* d_ws, size_t ws_size,
                              hipStream_t stream) {
    const float* cls = (const float*)d_in[0];   // (1,64,64,18) f32
    const float* dlt = (const float*)d_in[1];   // (1,64,64,36) f32
    float* out = (float*)d_out;                 // 300x5 f32
    char* ws = (char*)d_ws;
    u32*    ordsArr  = (u32*)   (ws);                    // 147456
    u64*    scat     = (u64*)   (ws + 147456);           // 294912
    float4* boxes    = (float4*)(ws + 442368);           // 589824
    float4* topBoxes = (float4*)(ws + 1032192);          // 96000
    u32*    slices   = (u32*)   (ws + 1128192);          // 36*3072*4 = 442368

    proposal_kernel<<<NSLICE, 1024, 0, stream>>>(cls, dlt, ordsArr, boxes, slices);
    select_nms_kernel<<<1, 1024, 0, stream>>>(ordsArr, boxes, slices, scat, topBoxes, out);
}